// Round 1
// baseline (995.329 us; speedup 1.0000x reference)
//
#include <hip/hip_runtime.h>
#include <math.h>

// Problem constants (match reference)
#define B_  4096
#define D_  1024
#define H_  2048
#define C_  1000
#define T_  819200
#define F_  32

// ---------------- workspace layout (bytes) ----------------
// [sums B*F f32][counts B f32][accum 8 f32] ... [combined B*D f32][hidden B*H f32]
// logits (B*C f32) aliases the combined buffer (combined is dead after GEMM1).
static const size_t WS_SUMS     = 0;
static const size_t WS_COUNTS   = WS_SUMS + (size_t)B_ * F_ * 4;
static const size_t WS_ACCUM    = WS_COUNTS + (size_t)B_ * 4;
static const size_t WS_ZERO_SZ  = WS_ACCUM + 32;                 // zeroed each launch
static const size_t WS_COMBINED = 1u << 20;                      // 1 MiB aligned
static const size_t WS_HIDDEN   = WS_COMBINED + (size_t)B_ * D_ * 4;
// total ≈ 49 MiB

// ---------------- segment mean: run-length reduce ----------------
// 32 lanes (one per feature col) walk RPT consecutive rows; atomics only on
// segment transitions (avg segment length ~200 rows).
#define RPT 32
__global__ __launch_bounds__(256) void seg_reduce_kernel(
    const float* __restrict__ var_flat, const int* __restrict__ seg_ids,
    float* __restrict__ sums, float* __restrict__ counts) {
  int gt  = blockIdx.x * blockDim.x + threadIdx.x;
  int col = gt & 31;
  long base = (long)(gt >> 5) * RPT;
  int cur = -1;
  float acc = 0.f, cnt = 0.f;
  for (int r = 0; r < RPT; ++r) {
    long row = base + r;
    int s   = seg_ids[row];
    float v = var_flat[row * F_ + col];
    if (s != cur) {
      if (cur >= 0) {
        atomicAdd(&sums[(size_t)cur * F_ + col], acc);
        if (col == 0) atomicAdd(&counts[cur], cnt);
      }
      cur = s; acc = 0.f; cnt = 0.f;
    }
    acc += v; cnt += 1.f;
  }
  if (cur >= 0) {
    atomicAdd(&sums[(size_t)cur * F_ + col], acc);
    if (col == 0) atomicAdd(&counts[cur], cnt);
  }
}

// ---------------- combined = feature + means @ Wv^T + bv ----------------
__global__ __launch_bounds__(256) void combined_kernel(
    const float* __restrict__ feat, const float* __restrict__ sums,
    const float* __restrict__ counts, const float* __restrict__ Wv,
    const float* __restrict__ bv, float* __restrict__ combined) {
  __shared__ float m[F_];
  int b  = blockIdx.y;
  int tid = threadIdx.x;
  if (tid < F_) {
    float c = counts[b];
    c = c < 1.f ? 1.f : c;
    m[tid] = sums[(size_t)b * F_ + tid] / c;
  }
  __syncthreads();
  int d = blockIdx.x * 256 + tid;
  float acc = feat[(size_t)b * D_ + d] + bv[d];
  const float4* wv = (const float4*)(Wv + (size_t)d * F_);
#pragma unroll
  for (int f4 = 0; f4 < F_ / 4; ++f4) {
    float4 w = wv[f4];
    acc += m[f4 * 4 + 0] * w.x + m[f4 * 4 + 1] * w.y +
           m[f4 * 4 + 2] * w.z + m[f4 * 4 + 3] * w.w;
  }
  combined[(size_t)b * D_ + d] = acc;
}

// ---------------- C = A @ B^T + bias (optional relu) ----------------
// A [M,K] rm, B [N,K] rm, C [M,N] rm. BM=BN=128, BK=8, 256 thr, 8x8/thread.
template <bool RELU>
__global__ __launch_bounds__(256) void gemm_bt_kernel(
    const float* __restrict__ A, const float* __restrict__ B,
    const float* __restrict__ bias, float* __restrict__ C,
    int M, int N, int K) {
  __shared__ float As[8][132];
  __shared__ float Bs[8][132];
  const int tid = threadIdx.x;
  const int bm = blockIdx.y * 128;
  const int bn = blockIdx.x * 128;
  const int tr = (tid >> 4) << 3;   // 0..120
  const int tc = (tid & 15) << 3;   // 0..120
  const int lr = tid >> 1;          // 0..127
  const int lk = (tid & 1) << 2;    // 0 or 4

  float acc[8][8];
#pragma unroll
  for (int i = 0; i < 8; ++i)
#pragma unroll
    for (int j = 0; j < 8; ++j) acc[i][j] = 0.f;

  const bool bvalid = (bn + lr) < N;
  const float* Ap = A + (size_t)(bm + lr) * K + lk;
  const float* Bp = B + (size_t)(bvalid ? (bn + lr) : 0) * K + lk;

  for (int k0 = 0; k0 < K; k0 += 8) {
    float4 a4 = *(const float4*)(Ap + k0);
    float4 b4 = make_float4(0.f, 0.f, 0.f, 0.f);
    if (bvalid) b4 = *(const float4*)(Bp + k0);
    __syncthreads();
    As[lk + 0][lr] = a4.x; As[lk + 1][lr] = a4.y;
    As[lk + 2][lr] = a4.z; As[lk + 3][lr] = a4.w;
    Bs[lk + 0][lr] = b4.x; Bs[lk + 1][lr] = b4.y;
    Bs[lk + 2][lr] = b4.z; Bs[lk + 3][lr] = b4.w;
    __syncthreads();
#pragma unroll
    for (int k = 0; k < 8; ++k) {
      float ar[8], br[8];
      *(float4*)(ar)     = *(const float4*)&As[k][tr];
      *(float4*)(ar + 4) = *(const float4*)&As[k][tr + 4];
      *(float4*)(br)     = *(const float4*)&Bs[k][tc];
      *(float4*)(br + 4) = *(const float4*)&Bs[k][tc + 4];
#pragma unroll
      for (int i = 0; i < 8; ++i)
#pragma unroll
        for (int j = 0; j < 8; ++j)
          acc[i][j] = fmaf(ar[i], br[j], acc[i][j]);
    }
  }

#pragma unroll
  for (int i = 0; i < 8; ++i) {
    float* crow = C + (size_t)(bm + tr + i) * N;
#pragma unroll
    for (int j = 0; j < 8; ++j) {
      int col = bn + tc + j;
      if (col < N) {
        float v = acc[i][j] + bias[col];
        if (RELU) v = v > 0.f ? v : 0.f;
        crow[col] = v;
      }
    }
  }
}

// ---------------- scalar head + MSE ----------------
__global__ __launch_bounds__(256) void scalar_loss_kernel(
    const float* __restrict__ hidden, const float* __restrict__ Ws,
    const float* __restrict__ bs, const float* __restrict__ tgt,
    float* __restrict__ accum) {
  int b = blockIdx.x;
  int tid = threadIdx.x;
  const float4* h4 = (const float4*)(hidden + (size_t)b * H_);
  const float4* w4 = (const float4*)Ws;
  float p = 0.f;
  for (int i = tid; i < H_ / 4; i += 256) {
    float4 a = h4[i], w = w4[i];
    p += a.x * w.x + a.y * w.y + a.z * w.z + a.w * w.w;
  }
#pragma unroll
  for (int o = 32; o > 0; o >>= 1) p += __shfl_down(p, o, 64);
  __shared__ float ss[4];
  if ((tid & 63) == 0) ss[tid >> 6] = p;
  __syncthreads();
  if (tid == 0) {
    float s = ss[0] + ss[1] + ss[2] + ss[3] + bs[0];
    float d = s - tgt[b];
    atomicAdd(&accum[2], d * d);
  }
}

// ---------------- softmax CE + accuracy ----------------
__global__ __launch_bounds__(256) void softmax_loss_kernel(
    const float* __restrict__ logits, const int* __restrict__ target,
    float* __restrict__ accum) {
  int b = blockIdx.x;
  int tid = threadIdx.x;
  const float* row = logits + (size_t)b * C_;
  float vmax = -INFINITY;
  int imax = 0x7fffffff;
  for (int c = tid; c < C_; c += 256) {
    float v = row[c];
    if (v > vmax) { vmax = v; imax = c; }
  }
  __shared__ float sv[4]; __shared__ int si[4];
#pragma unroll
  for (int o = 32; o > 0; o >>= 1) {
    float ov = __shfl_down(vmax, o, 64);
    int   oi = __shfl_down(imax, o, 64);
    if (ov > vmax || (ov == vmax && oi < imax)) { vmax = ov; imax = oi; }
  }
  int wid = tid >> 6;
  if ((tid & 63) == 0) { sv[wid] = vmax; si[wid] = imax; }
  __syncthreads();
  if (tid == 0) {
    for (int w = 1; w < 4; ++w)
      if (sv[w] > vmax || (sv[w] == vmax && si[w] < imax)) { vmax = sv[w]; imax = si[w]; }
    sv[0] = vmax; si[0] = imax;
  }
  __syncthreads();
  vmax = sv[0]; imax = si[0];
  float se = 0.f;
  for (int c = tid; c < C_; c += 256) se += expf(row[c] - vmax);
#pragma unroll
  for (int o = 32; o > 0; o >>= 1) se += __shfl_down(se, o, 64);
  __shared__ float ss[4];
  if ((tid & 63) == 0) ss[wid] = se;
  __syncthreads();
  if (tid == 0) {
    float tot = ss[0] + ss[1] + ss[2] + ss[3];
    int t = target[b];
    float logp = row[t] - vmax - logf(tot);
    atomicAdd(&accum[1], -logp);
    atomicAdd(&accum[3], (imax == t) ? 1.f : 0.f);
  }
}

// ---------------- finalize ----------------
__global__ void finalize_kernel(const float* __restrict__ accum,
                                float* __restrict__ out) {
  float lv = accum[1] * (1.f / B_);
  float ls = accum[2] * (1.f / B_);
  float ac = accum[3] * (1.f / B_);
  out[0] = lv + ls;
  out[1] = lv;
  out[2] = ls;
  out[3] = ac;
}

extern "C" void kernel_launch(void* const* d_in, const int* in_sizes, int n_in,
                              void* d_out, int out_size, void* d_ws, size_t ws_size,
                              hipStream_t stream) {
  const float* feature = (const float*)d_in[0];
  const float* var_flat = (const float*)d_in[1];
  const int*   seg_ids  = (const int*)d_in[2];
  const int*   tgt_vec  = (const int*)d_in[3];
  const float* tgt_scal = (const float*)d_in[4];
  const float* Wv = (const float*)d_in[5];
  const float* bv = (const float*)d_in[6];
  const float* W1 = (const float*)d_in[7];
  const float* b1 = (const float*)d_in[8];
  const float* W2 = (const float*)d_in[9];
  const float* b2 = (const float*)d_in[10];
  const float* Ws = (const float*)d_in[11];
  const float* bs = (const float*)d_in[12];
  float* out = (float*)d_out;

  char* ws = (char*)d_ws;
  float* sums     = (float*)(ws + WS_SUMS);
  float* counts   = (float*)(ws + WS_COUNTS);
  float* accum    = (float*)(ws + WS_ACCUM);
  float* combined = (float*)(ws + WS_COMBINED);
  float* hidden   = (float*)(ws + WS_HIDDEN);
  float* logits   = combined;  // alias: combined dead after GEMM1

  // zero the atomically-accumulated regions (ws is poisoned 0xAA each call)
  hipMemsetAsync(ws, 0, WS_ZERO_SZ, stream);

  // 1) segment sums/counts
  {
    int groups = T_ / RPT;                 // 25600
    int threads = groups * 32;             // 819200
    seg_reduce_kernel<<<threads / 256, 256, 0, stream>>>(var_flat, seg_ids, sums, counts);
  }

  // 2) combined = feature + means @ Wv^T + bv
  {
    dim3 grid(D_ / 256, B_);
    combined_kernel<<<grid, 256, 0, stream>>>(feature, sums, counts, Wv, bv, combined);
  }

  // 3) hidden = relu(combined @ W1^T + b1)   [4096 x 2048]
  {
    dim3 grid(H_ / 128, B_ / 128);
    gemm_bt_kernel<true><<<grid, 256, 0, stream>>>(combined, W1, b1, hidden, B_, H_, D_);
  }

  // 4) logits = hidden @ W2^T + b2           [4096 x 1000]
  {
    dim3 grid((C_ + 127) / 128, B_ / 128);
    gemm_bt_kernel<false><<<grid, 256, 0, stream>>>(hidden, W2, b2, logits, B_, C_, H_);
  }

  // 5) scalar head + MSE loss
  scalar_loss_kernel<<<B_, 256, 0, stream>>>(hidden, Ws, bs, tgt_scal, accum);

  // 6) softmax CE + accuracy
  softmax_loss_kernel<<<B_, 256, 0, stream>>>(logits, tgt_vec, accum);

  // 7) finalize the 4 scalars
  finalize_kernel<<<1, 1, 0, stream>>>(accum, out);
}

// Round 2
// 554.607 us; speedup vs baseline: 1.7947x; 1.7947x over previous
//
#include <hip/hip_runtime.h>
#include <hip/hip_bf16.h>
#include <math.h>

// Problem constants (match reference)
#define B_  4096
#define D_  1024
#define H_  2048
#define C_  1000
#define T_  819200
#define F_  32
#define NPAD2 1024   // W2 rows padded 1000 -> 1024

typedef __attribute__((ext_vector_type(8))) short short8;
typedef __attribute__((ext_vector_type(4))) float f32x4;

// ---------------- workspace layout (bytes) ----------------
static const size_t WS_SUMS     = 0;                               // B*F f32 = 512K
static const size_t WS_COUNTS   = WS_SUMS + (size_t)B_ * F_ * 4;   // B f32 = 16K
static const size_t WS_ACCUM    = WS_COUNTS + (size_t)B_ * 4;      // 8 f32
static const size_t WS_ZERO_SZ  = WS_ACCUM + 32;                   // zeroed each launch
static const size_t WS_COMBINED = 1u << 20;                        // B*D bf16 = 8 MiB
static const size_t WS_W1BF     = WS_COMBINED + (size_t)B_ * D_ * 2;   // 4 MiB
static const size_t WS_W2BF     = WS_W1BF + (size_t)H_ * D_ * 2;       // 4 MiB
static const size_t WS_HIDDEN   = WS_W2BF + (size_t)NPAD2 * H_ * 2;    // B*H bf16 = 16 MiB
static const size_t WS_LOGITS   = WS_HIDDEN + (size_t)B_ * H_ * 2;     // B*C f32 = 15.6 MiB
// total ~48.7 MiB

// ---------------- segment mean: run-length reduce ----------------
#define RPT 32
__global__ __launch_bounds__(256) void seg_reduce_kernel(
    const float* __restrict__ var_flat, const int* __restrict__ seg_ids,
    float* __restrict__ sums, float* __restrict__ counts) {
  int gt  = blockIdx.x * blockDim.x + threadIdx.x;
  int col = gt & 31;
  long base = (long)(gt >> 5) * RPT;
  int cur = -1;
  float acc = 0.f, cnt = 0.f;
  for (int r = 0; r < RPT; ++r) {
    long row = base + r;
    int s   = seg_ids[row];
    float v = var_flat[row * F_ + col];
    if (s != cur) {
      if (cur >= 0) {
        atomicAdd(&sums[(size_t)cur * F_ + col], acc);
        if (col == 0) atomicAdd(&counts[cur], cnt);
      }
      cur = s; acc = 0.f; cnt = 0.f;
    }
    acc += v; cnt += 1.f;
  }
  if (cur >= 0) {
    atomicAdd(&sums[(size_t)cur * F_ + col], acc);
    if (col == 0) atomicAdd(&counts[cur], cnt);
  }
}

// ---------------- fp32 -> bf16 weight conversion ----------------
__global__ __launch_bounds__(256) void cvt_bf16_kernel(
    const float* __restrict__ src, __hip_bfloat16* __restrict__ dst, int n8) {
  int i = blockIdx.x * 256 + threadIdx.x;
  if (i >= n8) return;
  size_t off = (size_t)i * 8;
  float4 a = *(const float4*)(src + off);
  float4 b = *(const float4*)(src + off + 4);
  __hip_bfloat16 t[8];
  t[0] = __float2bfloat16(a.x); t[1] = __float2bfloat16(a.y);
  t[2] = __float2bfloat16(a.z); t[3] = __float2bfloat16(a.w);
  t[4] = __float2bfloat16(b.x); t[5] = __float2bfloat16(b.y);
  t[6] = __float2bfloat16(b.z); t[7] = __float2bfloat16(b.w);
  *(uint4*)(dst + off) = *(uint4*)t;
}

// W2 [C_,H_] fp32 -> padded [NPAD2,H_] bf16 (rows >= C_ zeroed)
__global__ __launch_bounds__(256) void cvt_w2_kernel(
    const float* __restrict__ src, __hip_bfloat16* __restrict__ dst) {
  int i = blockIdx.x * 256 + threadIdx.x;      // one per 8 elements
  size_t off = (size_t)i * 8;
  int row = (int)(off / H_);
  __hip_bfloat16 t[8];
  if (row < C_) {
    float4 a = *(const float4*)(src + off);
    float4 b = *(const float4*)(src + off + 4);
    t[0] = __float2bfloat16(a.x); t[1] = __float2bfloat16(a.y);
    t[2] = __float2bfloat16(a.z); t[3] = __float2bfloat16(a.w);
    t[4] = __float2bfloat16(b.x); t[5] = __float2bfloat16(b.y);
    t[6] = __float2bfloat16(b.z); t[7] = __float2bfloat16(b.w);
  } else {
    for (int e = 0; e < 8; ++e) t[e] = __float2bfloat16(0.f);
  }
  *(uint4*)(dst + off) = *(uint4*)t;
}

// ---------------- combined = feature + means @ Wv^T + bv (bf16 out) -------
__global__ __launch_bounds__(256) void combined_kernel(
    const float* __restrict__ feat, const float* __restrict__ sums,
    const float* __restrict__ counts, const float* __restrict__ Wv,
    const float* __restrict__ bv, __hip_bfloat16* __restrict__ combined) {
  __shared__ float m[F_];
  int b  = blockIdx.y;
  int tid = threadIdx.x;
  if (tid < F_) {
    float c = counts[b];
    c = c < 1.f ? 1.f : c;
    m[tid] = sums[(size_t)b * F_ + tid] / c;
  }
  __syncthreads();
  int d = blockIdx.x * 256 + tid;
  float acc = feat[(size_t)b * D_ + d] + bv[d];
  const float4* wv = (const float4*)(Wv + (size_t)d * F_);
#pragma unroll
  for (int f4 = 0; f4 < F_ / 4; ++f4) {
    float4 w = wv[f4];
    acc += m[f4 * 4 + 0] * w.x + m[f4 * 4 + 1] * w.y +
           m[f4 * 4 + 2] * w.z + m[f4 * 4 + 3] * w.w;
  }
  combined[(size_t)b * D_ + d] = __float2bfloat16(acc);
}

// ---------------- MFMA bf16 GEMM: C = A @ B^T + bias ----------------
// A [M,K] bf16 rm, B [Npad,K] bf16 rm. 128x128 tile, BK=32, 256 thr (4 waves),
// each wave a 64x64 subtile = 4x4 of 16x16x32 MFMAs.
// LDS k-major-chunk layout: element (row,k) at [ (k>>3)*1024 + row*8 + (k&7) ]
// -> ds_read_b128 frag reads are 2-way bank aliased (free), and
//    global_load_lds staging is lane-contiguous as required.
__device__ inline void load16_lds(const short* g, short* l) {
  __builtin_amdgcn_global_load_lds(
      (const __attribute__((address_space(1))) void*)g,
      (__attribute__((address_space(3))) void*)l, 16, 0, 0);
}

template <int MODE>  // 0: relu + bf16 out (Nout=stride, no mask); 1: f32 out, col<Nout masked
__global__ __launch_bounds__(256) void gemm_mfma_kernel(
    const short* __restrict__ A, const short* __restrict__ Bm,
    const float* __restrict__ bias, void* __restrict__ Cout,
    int M, int K, int Nout) {
  __shared__ short As[4096];  // 8 KB
  __shared__ short Bs[4096];  // 8 KB
  const int tid  = threadIdx.x;
  const int lane = tid & 63;
  const int w    = tid >> 6;
  const int bm = blockIdx.y * 128;
  const int bn = blockIdx.x * 128;
  const int wm = (w >> 1) * 64;
  const int wn = (w & 1) * 64;
  const int m_lane = lane & 15;
  const int quad   = lane >> 4;

  f32x4 acc[4][4];
#pragma unroll
  for (int i = 0; i < 4; ++i)
#pragma unroll
    for (int j = 0; j < 4; ++j) acc[i][j] = f32x4{0.f, 0.f, 0.f, 0.f};

  // staging: chunk c (of 512 16B chunks) holds (kc=c>>7, row=c&127);
  // wave w stages chunks [w*128, w*128+128) via 2 instructions of 64 lanes.
  const int c0 = w * 128 + lane;
  const int c1 = c0 + 64;
  const short* gA0 = A + (size_t)(bm + (c0 & 127)) * K + (c0 >> 7) * 8;
  const short* gA1 = A + (size_t)(bm + (c1 & 127)) * K + (c1 >> 7) * 8;
  const short* gB0 = Bm + (size_t)(bn + (c0 & 127)) * K + (c0 >> 7) * 8;
  const short* gB1 = Bm + (size_t)(bn + (c1 & 127)) * K + (c1 >> 7) * 8;
  short* lA0 = As + (size_t)w * 1024;
  short* lA1 = lA0 + 512;
  short* lB0 = Bs + (size_t)w * 1024;
  short* lB1 = lB0 + 512;

  for (int k0 = 0; k0 < K; k0 += 32) {
    __syncthreads();
    load16_lds(gA0 + k0, lA0);
    load16_lds(gA1 + k0, lA1);
    load16_lds(gB0 + k0, lB0);
    load16_lds(gB1 + k0, lB1);
    __syncthreads();
    short8 af[4], bf[4];
#pragma unroll
    for (int i = 0; i < 4; ++i)
      af[i] = *(const short8*)&As[quad * 1024 + (wm + i * 16 + m_lane) * 8];
#pragma unroll
    for (int j = 0; j < 4; ++j)
      bf[j] = *(const short8*)&Bs[quad * 1024 + (wn + j * 16 + m_lane) * 8];
#pragma unroll
    for (int i = 0; i < 4; ++i)
#pragma unroll
      for (int j = 0; j < 4; ++j)
        acc[i][j] = __builtin_amdgcn_mfma_f32_16x16x32_bf16(af[i], bf[j], acc[i][j], 0, 0, 0);
  }

  // epilogue: C/D layout col=lane&15, row=quad*4+reg
  const int row0 = bm + wm + quad * 4;
  const int col0 = bn + wn + m_lane;
  if (MODE == 0) {
    __hip_bfloat16* Cb = (__hip_bfloat16*)Cout;
#pragma unroll
    for (int j = 0; j < 4; ++j) {
      int col = col0 + j * 16;
      float bsv = bias[col];
#pragma unroll
      for (int i = 0; i < 4; ++i) {
#pragma unroll
        for (int r = 0; r < 4; ++r) {
          int row = row0 + i * 16 + r;
          float v = acc[i][j][r] + bsv;
          v = v > 0.f ? v : 0.f;
          Cb[(size_t)row * Nout + col] = __float2bfloat16(v);
        }
      }
    }
  } else {
    float* Cf = (float*)Cout;
#pragma unroll
    for (int j = 0; j < 4; ++j) {
      int col = col0 + j * 16;
      if (col < Nout) {
        float bsv = bias[col];
#pragma unroll
        for (int i = 0; i < 4; ++i) {
#pragma unroll
          for (int r = 0; r < 4; ++r) {
            int row = row0 + i * 16 + r;
            Cf[(size_t)row * Nout + col] = acc[i][j][r] + bsv;
          }
        }
      }
    }
  }
}

// ---------------- scalar head + MSE (bf16 hidden) ----------------
__global__ __launch_bounds__(256) void scalar_loss_kernel(
    const __hip_bfloat16* __restrict__ hidden, const float* __restrict__ Ws,
    const float* __restrict__ bs, const float* __restrict__ tgt,
    float* __restrict__ accum) {
  int b = blockIdx.x;
  int tid = threadIdx.x;
  const uint4* h4 = (const uint4*)(hidden + (size_t)b * H_);
  uint4 p = h4[tid];  // 8 bf16
  const float4* w4 = (const float4*)(Ws + (size_t)tid * 8);
  float4 w0 = w4[0], w1 = w4[1];
  float a0 = __uint_as_float(p.x << 16), a1 = __uint_as_float(p.x & 0xffff0000u);
  float a2 = __uint_as_float(p.y << 16), a3 = __uint_as_float(p.y & 0xffff0000u);
  float a4 = __uint_as_float(p.z << 16), a5 = __uint_as_float(p.z & 0xffff0000u);
  float a6 = __uint_as_float(p.w << 16), a7 = __uint_as_float(p.w & 0xffff0000u);
  float s = a0 * w0.x + a1 * w0.y + a2 * w0.z + a3 * w0.w +
            a4 * w1.x + a5 * w1.y + a6 * w1.z + a7 * w1.w;
#pragma unroll
  for (int o = 32; o > 0; o >>= 1) s += __shfl_down(s, o, 64);
  __shared__ float ss[4];
  if ((tid & 63) == 0) ss[tid >> 6] = s;
  __syncthreads();
  if (tid == 0) {
    float t = ss[0] + ss[1] + ss[2] + ss[3] + bs[0];
    float d = t - tgt[b];
    atomicAdd(&accum[2], d * d);
  }
}

// ---------------- softmax CE + accuracy ----------------
__global__ __launch_bounds__(256) void softmax_loss_kernel(
    const float* __restrict__ logits, const int* __restrict__ target,
    float* __restrict__ accum) {
  int b = blockIdx.x;
  int tid = threadIdx.x;
  const float* row = logits + (size_t)b * C_;
  float vmax = -INFINITY;
  int imax = 0x7fffffff;
  for (int c = tid; c < C_; c += 256) {
    float v = row[c];
    if (v > vmax) { vmax = v; imax = c; }
  }
  __shared__ float sv[4]; __shared__ int si[4];
#pragma unroll
  for (int o = 32; o > 0; o >>= 1) {
    float ov = __shfl_down(vmax, o, 64);
    int   oi = __shfl_down(imax, o, 64);
    if (ov > vmax || (ov == vmax && oi < imax)) { vmax = ov; imax = oi; }
  }
  int wid = tid >> 6;
  if ((tid & 63) == 0) { sv[wid] = vmax; si[wid] = imax; }
  __syncthreads();
  if (tid == 0) {
    for (int w = 1; w < 4; ++w)
      if (sv[w] > vmax || (sv[w] == vmax && si[w] < imax)) { vmax = sv[w]; imax = si[w]; }
    sv[0] = vmax; si[0] = imax;
  }
  __syncthreads();
  vmax = sv[0]; imax = si[0];
  float se = 0.f;
  for (int c = tid; c < C_; c += 256) se += expf(row[c] - vmax);
#pragma unroll
  for (int o = 32; o > 0; o >>= 1) se += __shfl_down(se, o, 64);
  __shared__ float ss[4];
  if ((tid & 63) == 0) ss[wid] = se;
  __syncthreads();
  if (tid == 0) {
    float tot = ss[0] + ss[1] + ss[2] + ss[3];
    int t = target[b];
    float logp = row[t] - vmax - logf(tot);
    atomicAdd(&accum[1], -logp);
    atomicAdd(&accum[3], (imax == t) ? 1.f : 0.f);
  }
}

// ---------------- finalize ----------------
__global__ void finalize_kernel(const float* __restrict__ accum,
                                float* __restrict__ out) {
  float lv = accum[1] * (1.f / B_);
  float ls = accum[2] * (1.f / B_);
  float ac = accum[3] * (1.f / B_);
  out[0] = lv + ls;
  out[1] = lv;
  out[2] = ls;
  out[3] = ac;
}

extern "C" void kernel_launch(void* const* d_in, const int* in_sizes, int n_in,
                              void* d_out, int out_size, void* d_ws, size_t ws_size,
                              hipStream_t stream) {
  const float* feature  = (const float*)d_in[0];
  const float* var_flat = (const float*)d_in[1];
  const int*   seg_ids  = (const int*)d_in[2];
  const int*   tgt_vec  = (const int*)d_in[3];
  const float* tgt_scal = (const float*)d_in[4];
  const float* Wv = (const float*)d_in[5];
  const float* bv = (const float*)d_in[6];
  const float* W1 = (const float*)d_in[7];
  const float* b1 = (const float*)d_in[8];
  const float* W2 = (const float*)d_in[9];
  const float* b2 = (const float*)d_in[10];
  const float* Ws = (const float*)d_in[11];
  const float* bs = (const float*)d_in[12];
  float* out = (float*)d_out;

  char* ws = (char*)d_ws;
  float* sums   = (float*)(ws + WS_SUMS);
  float* counts = (float*)(ws + WS_COUNTS);
  float* accum  = (float*)(ws + WS_ACCUM);
  __hip_bfloat16* combined_bf = (__hip_bfloat16*)(ws + WS_COMBINED);
  __hip_bfloat16* W1bf        = (__hip_bfloat16*)(ws + WS_W1BF);
  __hip_bfloat16* W2bf        = (__hip_bfloat16*)(ws + WS_W2BF);
  __hip_bfloat16* hidden_bf   = (__hip_bfloat16*)(ws + WS_HIDDEN);
  float*          logits      = (float*)(ws + WS_LOGITS);

  hipMemsetAsync(ws, 0, WS_ZERO_SZ, stream);

  // 1) segment sums/counts
  seg_reduce_kernel<<<(T_ / RPT) * 32 / 256, 256, 0, stream>>>(var_flat, seg_ids, sums, counts);

  // 2) weight conversions
  cvt_bf16_kernel<<<(H_ * D_ / 8 + 255) / 256, 256, 0, stream>>>(W1, W1bf, H_ * D_ / 8);
  cvt_w2_kernel<<<(NPAD2 * H_ / 8) / 256, 256, 0, stream>>>(W2, W2bf);

  // 3) combined = feature + means @ Wv^T + bv  (bf16)
  {
    dim3 grid(D_ / 256, B_);
    combined_kernel<<<grid, 256, 0, stream>>>(feature, sums, counts, Wv, bv, combined_bf);
  }

  // 4) hidden = relu(combined @ W1^T + b1)  [4096 x 2048] bf16, MFMA
  {
    dim3 grid(H_ / 128, B_ / 128);
    gemm_mfma_kernel<0><<<grid, 256, 0, stream>>>(
        (const short*)combined_bf, (const short*)W1bf, b1, hidden_bf, B_, D_, H_);
  }

  // 5) logits = hidden @ W2^T + b2  [4096 x 1000] f32, MFMA (Npad=1024)
  {
    dim3 grid(NPAD2 / 128, B_ / 128);
    gemm_mfma_kernel<1><<<grid, 256, 0, stream>>>(
        (const short*)hidden_bf, (const short*)W2bf, b2, logits, B_, H_, C_);
  }

  // 6) scalar head + MSE
  scalar_loss_kernel<<<B_, 256, 0, stream>>>(hidden_bf, Ws, bs, tgt_scal, accum);

  // 7) softmax CE + accuracy
  softmax_loss_kernel<<<B_, 256, 0, stream>>>(logits, tgt_vec, accum);

  // 8) finalize
  finalize_kernel<<<1, 1, 0, stream>>>(accum, out);
}

// Round 3
// 351.300 us; speedup vs baseline: 2.8333x; 1.5787x over previous
//
#include <hip/hip_runtime.h>
#include <hip/hip_bf16.h>
#include <math.h>

// Problem constants (match reference)
#define B_  4096
#define D_  1024
#define H_  2048
#define C_  1000
#define T_  819200
#define F_  32
#define NPAD2 1024   // W2 rows padded 1000 -> 1024
#define NPART 1024   // loss partial blocks (B_/4)

typedef __attribute__((ext_vector_type(8))) short short8;
typedef __attribute__((ext_vector_type(4))) float f32x4;

// ---------------- workspace layout (bytes) ----------------
static const size_t WS_SUMS     = 0;                               // B*F f32 = 512K
static const size_t WS_COUNTS   = WS_SUMS + (size_t)B_ * F_ * 4;   // B f32 = 16K
static const size_t WS_ZERO_SZ  = WS_COUNTS + (size_t)B_ * 4;      // zeroed each launch
static const size_t WS_PV       = WS_ZERO_SZ;                      // NPART f32 (no zero needed)
static const size_t WS_PA       = WS_PV + NPART * 4;
static const size_t WS_PS       = WS_PA + NPART * 4;
static const size_t WS_COMBINED = 1u << 20;                        // B*D bf16 = 8 MiB
static const size_t WS_W1BF     = WS_COMBINED + (size_t)B_ * D_ * 2;   // 4 MiB
static const size_t WS_W2BF     = WS_W1BF + (size_t)H_ * D_ * 2;       // 4 MiB
static const size_t WS_HIDDEN   = WS_W2BF + (size_t)NPAD2 * H_ * 2;    // B*H bf16 = 16 MiB
static const size_t WS_LOGITS   = WS_HIDDEN + (size_t)B_ * H_ * 2;     // B*C f32 = 15.6 MiB

// ---------------- segment mean: run-length reduce (float4) ----------------
// 8 lanes per row-group (4 cols each) walk RPT consecutive rows; atomics only
// at segment transitions (avg segment ~200 rows).
#define RPT 32
__global__ __launch_bounds__(256) void seg_reduce_kernel(
    const float* __restrict__ var_flat, const int* __restrict__ seg_ids,
    float* __restrict__ sums, float* __restrict__ counts) {
  int gt  = blockIdx.x * 256 + threadIdx.x;
  int c4  = (gt & 7) * 4;
  long base = (long)(gt >> 3) * RPT;
  int cur = -1;
  float a0 = 0.f, a1 = 0.f, a2 = 0.f, a3 = 0.f, cnt = 0.f;
  for (int r = 0; r < RPT; ++r) {
    long row = base + r;
    int s = seg_ids[row];
    float4 v = *(const float4*)(var_flat + row * F_ + c4);
    if (s != cur) {
      if (cur >= 0) {
        float* dst = &sums[(size_t)cur * F_ + c4];
        atomicAdd(dst + 0, a0); atomicAdd(dst + 1, a1);
        atomicAdd(dst + 2, a2); atomicAdd(dst + 3, a3);
        if (c4 == 0) atomicAdd(&counts[cur], cnt);
      }
      cur = s; a0 = a1 = a2 = a3 = 0.f; cnt = 0.f;
    }
    a0 += v.x; a1 += v.y; a2 += v.z; a3 += v.w; cnt += 1.f;
  }
  if (cur >= 0) {
    float* dst = &sums[(size_t)cur * F_ + c4];
    atomicAdd(dst + 0, a0); atomicAdd(dst + 1, a1);
    atomicAdd(dst + 2, a2); atomicAdd(dst + 3, a3);
    if (c4 == 0) atomicAdd(&counts[cur], cnt);
  }
}

// ---------------- fp32 -> bf16 weight conversion ----------------
__global__ __launch_bounds__(256) void cvt_bf16_kernel(
    const float* __restrict__ src, __hip_bfloat16* __restrict__ dst, int n8) {
  int i = blockIdx.x * 256 + threadIdx.x;
  if (i >= n8) return;
  size_t off = (size_t)i * 8;
  float4 a = *(const float4*)(src + off);
  float4 b = *(const float4*)(src + off + 4);
  __hip_bfloat16 t[8];
  t[0] = __float2bfloat16(a.x); t[1] = __float2bfloat16(a.y);
  t[2] = __float2bfloat16(a.z); t[3] = __float2bfloat16(a.w);
  t[4] = __float2bfloat16(b.x); t[5] = __float2bfloat16(b.y);
  t[6] = __float2bfloat16(b.z); t[7] = __float2bfloat16(b.w);
  *(uint4*)(dst + off) = *(uint4*)t;
}

// W2 [C_,H_] fp32 -> padded [NPAD2,H_] bf16 (rows >= C_ zeroed)
__global__ __launch_bounds__(256) void cvt_w2_kernel(
    const float* __restrict__ src, __hip_bfloat16* __restrict__ dst) {
  int i = blockIdx.x * 256 + threadIdx.x;
  size_t off = (size_t)i * 8;
  int row = (int)(off / H_);
  __hip_bfloat16 t[8];
  if (row < C_) {
    float4 a = *(const float4*)(src + off);
    float4 b = *(const float4*)(src + off + 4);
    t[0] = __float2bfloat16(a.x); t[1] = __float2bfloat16(a.y);
    t[2] = __float2bfloat16(a.z); t[3] = __float2bfloat16(a.w);
    t[4] = __float2bfloat16(b.x); t[5] = __float2bfloat16(b.y);
    t[6] = __float2bfloat16(b.z); t[7] = __float2bfloat16(b.w);
  } else {
    for (int e = 0; e < 8; ++e) t[e] = __float2bfloat16(0.f);
  }
  *(uint4*)(dst + off) = *(uint4*)t;
}

// ---------------- combined = feature + means @ Wv^T + bv (bf16 out) -------
// 8 batch rows per block: Wv row loaded once per thread, reused 8x.
__global__ __launch_bounds__(256) void combined_kernel(
    const float* __restrict__ feat, const float* __restrict__ sums,
    const float* __restrict__ counts, const float* __restrict__ Wv,
    const float* __restrict__ bv, __hip_bfloat16* __restrict__ combined) {
  __shared__ float m[8][F_];
  int b0  = blockIdx.y * 8;
  int tid = threadIdx.x;
  {
    int seg = tid >> 5, col = tid & 31;
    float c = counts[b0 + seg];
    c = c < 1.f ? 1.f : c;
    m[seg][col] = sums[(size_t)(b0 + seg) * F_ + col] / c;
  }
  __syncthreads();
  int d = blockIdx.x * 256 + tid;
  float w[F_];
  {
    const float4* wv = (const float4*)(Wv + (size_t)d * F_);
#pragma unroll
    for (int f4 = 0; f4 < F_ / 4; ++f4) {
      float4 x = wv[f4];
      w[f4 * 4 + 0] = x.x; w[f4 * 4 + 1] = x.y;
      w[f4 * 4 + 2] = x.z; w[f4 * 4 + 3] = x.w;
    }
  }
  float bvd = bv[d];
#pragma unroll
  for (int bb = 0; bb < 8; ++bb) {
    float acc = feat[(size_t)(b0 + bb) * D_ + d] + bvd;
#pragma unroll
    for (int f = 0; f < F_; ++f) acc = fmaf(m[bb][f], w[f], acc);
    combined[(size_t)(b0 + bb) * D_ + d] = __float2bfloat16(acc);
  }
}

// ---------------- MFMA bf16 GEMM: C = A @ B^T + bias ----------------
__device__ inline void load16_lds(const short* g, short* l) {
  __builtin_amdgcn_global_load_lds(
      (const __attribute__((address_space(1))) void*)g,
      (__attribute__((address_space(3))) void*)l, 16, 0, 0);
}

template <int MODE>  // 0: relu + bf16 out; 1: f32 out, col<Nout masked
__global__ __launch_bounds__(256) void gemm_mfma_kernel(
    const short* __restrict__ A, const short* __restrict__ Bm,
    const float* __restrict__ bias, void* __restrict__ Cout,
    int M, int K, int Nout) {
  __shared__ short As[4096];
  __shared__ short Bs[4096];
  const int tid  = threadIdx.x;
  const int lane = tid & 63;
  const int w    = tid >> 6;
  const int bm = blockIdx.y * 128;
  const int bn = blockIdx.x * 128;
  const int wm = (w >> 1) * 64;
  const int wn = (w & 1) * 64;
  const int m_lane = lane & 15;
  const int quad   = lane >> 4;

  f32x4 acc[4][4];
#pragma unroll
  for (int i = 0; i < 4; ++i)
#pragma unroll
    for (int j = 0; j < 4; ++j) acc[i][j] = f32x4{0.f, 0.f, 0.f, 0.f};

  const int c0 = w * 128 + lane;
  const int c1 = c0 + 64;
  const short* gA0 = A + (size_t)(bm + (c0 & 127)) * K + (c0 >> 7) * 8;
  const short* gA1 = A + (size_t)(bm + (c1 & 127)) * K + (c1 >> 7) * 8;
  const short* gB0 = Bm + (size_t)(bn + (c0 & 127)) * K + (c0 >> 7) * 8;
  const short* gB1 = Bm + (size_t)(bn + (c1 & 127)) * K + (c1 >> 7) * 8;
  short* lA0 = As + (size_t)w * 1024;
  short* lA1 = lA0 + 512;
  short* lB0 = Bs + (size_t)w * 1024;
  short* lB1 = lB0 + 512;

  for (int k0 = 0; k0 < K; k0 += 32) {
    __syncthreads();
    load16_lds(gA0 + k0, lA0);
    load16_lds(gA1 + k0, lA1);
    load16_lds(gB0 + k0, lB0);
    load16_lds(gB1 + k0, lB1);
    __syncthreads();
    short8 af[4], bf[4];
#pragma unroll
    for (int i = 0; i < 4; ++i)
      af[i] = *(const short8*)&As[quad * 1024 + (wm + i * 16 + m_lane) * 8];
#pragma unroll
    for (int j = 0; j < 4; ++j)
      bf[j] = *(const short8*)&Bs[quad * 1024 + (wn + j * 16 + m_lane) * 8];
#pragma unroll
    for (int i = 0; i < 4; ++i)
#pragma unroll
      for (int j = 0; j < 4; ++j)
        acc[i][j] = __builtin_amdgcn_mfma_f32_16x16x32_bf16(af[i], bf[j], acc[i][j], 0, 0, 0);
  }

  const int row0 = bm + wm + quad * 4;
  const int col0 = bn + wn + m_lane;
  if (MODE == 0) {
    __hip_bfloat16* Cb = (__hip_bfloat16*)Cout;
#pragma unroll
    for (int j = 0; j < 4; ++j) {
      int col = col0 + j * 16;
      float bsv = bias[col];
#pragma unroll
      for (int i = 0; i < 4; ++i)
#pragma unroll
        for (int r = 0; r < 4; ++r) {
          int row = row0 + i * 16 + r;
          float v = acc[i][j][r] + bsv;
          v = v > 0.f ? v : 0.f;
          Cb[(size_t)row * Nout + col] = __float2bfloat16(v);
        }
    }
  } else {
    float* Cf = (float*)Cout;
#pragma unroll
    for (int j = 0; j < 4; ++j) {
      int col = col0 + j * 16;
      if (col < Nout) {
        float bsv = bias[col];
#pragma unroll
        for (int i = 0; i < 4; ++i)
#pragma unroll
          for (int r = 0; r < 4; ++r) {
            int row = row0 + i * 16 + r;
            Cf[(size_t)row * Nout + col] = acc[i][j][r] + bsv;
          }
      }
    }
  }
}

// ---------------- scalar head + MSE: 1 wave/row, partials, no atomics -----
__global__ __launch_bounds__(256) void scalar_loss_kernel(
    const __hip_bfloat16* __restrict__ hidden, const float* __restrict__ Ws,
    const float* __restrict__ bs, const float* __restrict__ tgt,
    float* __restrict__ ps) {
  int tid  = threadIdx.x;
  int lane = tid & 63;
  int w    = tid >> 6;
  int b    = blockIdx.x * 4 + w;
  const uint4*  h4 = (const uint4*)(hidden + (size_t)b * H_);   // 256 chunks of 8 bf16
  const float4* w4 = (const float4*)Ws;
  float s = 0.f;
#pragma unroll
  for (int k = 0; k < 4; ++k) {
    int ch = lane + 64 * k;
    uint4 p = h4[ch];
    float4 w0 = w4[2 * ch], w1 = w4[2 * ch + 1];
    float a0 = __uint_as_float(p.x << 16), a1 = __uint_as_float(p.x & 0xffff0000u);
    float a2 = __uint_as_float(p.y << 16), a3 = __uint_as_float(p.y & 0xffff0000u);
    float a4 = __uint_as_float(p.z << 16), a5 = __uint_as_float(p.z & 0xffff0000u);
    float a6 = __uint_as_float(p.w << 16), a7 = __uint_as_float(p.w & 0xffff0000u);
    s += a0 * w0.x + a1 * w0.y + a2 * w0.z + a3 * w0.w +
         a4 * w1.x + a5 * w1.y + a6 * w1.z + a7 * w1.w;
  }
#pragma unroll
  for (int o = 32; o > 0; o >>= 1) s += __shfl_down(s, o, 64);
  __shared__ float sq[4];
  if (lane == 0) {
    float d = s + bs[0] - tgt[b];
    sq[w] = d * d;
  }
  __syncthreads();
  if (tid == 0) ps[blockIdx.x] = sq[0] + sq[1] + sq[2] + sq[3];
}

// ---------------- softmax CE + accuracy: 1 wave/row, register-resident ----
__global__ __launch_bounds__(256) void softmax_loss_kernel(
    const float* __restrict__ logits, const int* __restrict__ target,
    float* __restrict__ pv, float* __restrict__ pa) {
  int tid  = threadIdx.x;
  int lane = tid & 63;
  int w    = tid >> 6;
  int b    = blockIdx.x * 4 + w;
  const float*  row  = logits + (size_t)b * C_;
  const float4* row4 = (const float4*)row;
  const int C4 = C_ / 4;   // 250
  float v[16];
  float vmax = -INFINITY;
  int   imax = 0x7fffffff;
#pragma unroll
  for (int k = 0; k < 4; ++k) {
    int c4 = lane + 64 * k;
    float4 x = (c4 < C4) ? row4[c4]
                         : make_float4(-INFINITY, -INFINITY, -INFINITY, -INFINITY);
    v[k * 4 + 0] = x.x; v[k * 4 + 1] = x.y; v[k * 4 + 2] = x.z; v[k * 4 + 3] = x.w;
#pragma unroll
    for (int e = 0; e < 4; ++e) {
      float val = v[k * 4 + e];
      int   idx = c4 * 4 + e;
      if (val > vmax) { vmax = val; imax = idx; }
    }
  }
#pragma unroll
  for (int o = 32; o > 0; o >>= 1) {
    float ov = __shfl_down(vmax, o, 64);
    int   oi = __shfl_down(imax, o, 64);
    if (ov > vmax || (ov == vmax && oi < imax)) { vmax = ov; imax = oi; }
  }
  vmax = __shfl(vmax, 0, 64);   // broadcast max for exp pass
  float se = 0.f;
#pragma unroll
  for (int j = 0; j < 16; ++j) se += expf(v[j] - vmax);
#pragma unroll
  for (int o = 32; o > 0; o >>= 1) se += __shfl_down(se, o, 64);
  __shared__ float s_nll[4];
  __shared__ float s_acc[4];
  if (lane == 0) {
    int t = target[b];
    float logp = row[t] - vmax - logf(se);
    s_nll[w] = -logp;
    s_acc[w] = (imax == t) ? 1.f : 0.f;
  }
  __syncthreads();
  if (tid == 0) {
    pv[blockIdx.x] = s_nll[0] + s_nll[1] + s_nll[2] + s_nll[3];
    pa[blockIdx.x] = s_acc[0] + s_acc[1] + s_acc[2] + s_acc[3];
  }
}

// ---------------- finalize: reduce partials ----------------
__global__ __launch_bounds__(256) void finalize_kernel(
    const float* __restrict__ pv, const float* __restrict__ pa,
    const float* __restrict__ ps, float* __restrict__ out) {
  int tid  = threadIdx.x;
  int lane = tid & 63;
  int w    = tid >> 6;
  float nll = 0.f, acc = 0.f, sq = 0.f;
  for (int i = tid; i < NPART; i += 256) {
    nll += pv[i]; acc += pa[i]; sq += ps[i];
  }
#pragma unroll
  for (int o = 32; o > 0; o >>= 1) {
    nll += __shfl_down(nll, o, 64);
    acc += __shfl_down(acc, o, 64);
    sq  += __shfl_down(sq,  o, 64);
  }
  __shared__ float sn[4], sa[4], ss[4];
  if (lane == 0) { sn[w] = nll; sa[w] = acc; ss[w] = sq; }
  __syncthreads();
  if (tid == 0) {
    float lv = (sn[0] + sn[1] + sn[2] + sn[3]) * (1.f / B_);
    float ls = (ss[0] + ss[1] + ss[2] + ss[3]) * (1.f / B_);
    float ac = (sa[0] + sa[1] + sa[2] + sa[3]) * (1.f / B_);
    out[0] = lv + ls;
    out[1] = lv;
    out[2] = ls;
    out[3] = ac;
  }
}

extern "C" void kernel_launch(void* const* d_in, const int* in_sizes, int n_in,
                              void* d_out, int out_size, void* d_ws, size_t ws_size,
                              hipStream_t stream) {
  const float* feature  = (const float*)d_in[0];
  const float* var_flat = (const float*)d_in[1];
  const int*   seg_ids  = (const int*)d_in[2];
  const int*   tgt_vec  = (const int*)d_in[3];
  const float* tgt_scal = (const float*)d_in[4];
  const float* Wv = (const float*)d_in[5];
  const float* bv = (const float*)d_in[6];
  const float* W1 = (const float*)d_in[7];
  const float* b1 = (const float*)d_in[8];
  const float* W2 = (const float*)d_in[9];
  const float* b2 = (const float*)d_in[10];
  const float* Ws = (const float*)d_in[11];
  const float* bs = (const float*)d_in[12];
  float* out = (float*)d_out;

  char* ws = (char*)d_ws;
  float* sums   = (float*)(ws + WS_SUMS);
  float* counts = (float*)(ws + WS_COUNTS);
  float* pv     = (float*)(ws + WS_PV);
  float* pa     = (float*)(ws + WS_PA);
  float* ps     = (float*)(ws + WS_PS);
  __hip_bfloat16* combined_bf = (__hip_bfloat16*)(ws + WS_COMBINED);
  __hip_bfloat16* W1bf        = (__hip_bfloat16*)(ws + WS_W1BF);
  __hip_bfloat16* W2bf        = (__hip_bfloat16*)(ws + WS_W2BF);
  __hip_bfloat16* hidden_bf   = (__hip_bfloat16*)(ws + WS_HIDDEN);
  float*          logits      = (float*)(ws + WS_LOGITS);

  hipMemsetAsync(ws, 0, WS_ZERO_SZ, stream);

  // 1) segment sums/counts (float4, 8 lanes/row-group)
  seg_reduce_kernel<<<(T_ / RPT) * 8 / 256, 256, 0, stream>>>(var_flat, seg_ids, sums, counts);

  // 2) weight conversions
  cvt_bf16_kernel<<<(H_ * D_ / 8 + 255) / 256, 256, 0, stream>>>(W1, W1bf, H_ * D_ / 8);
  cvt_w2_kernel<<<(NPAD2 * H_ / 8) / 256, 256, 0, stream>>>(W2, W2bf);

  // 3) combined = feature + means @ Wv^T + bv  (bf16, 8 rows/block)
  {
    dim3 grid(D_ / 256, B_ / 8);
    combined_kernel<<<grid, 256, 0, stream>>>(feature, sums, counts, Wv, bv, combined_bf);
  }

  // 4) hidden = relu(combined @ W1^T + b1)  [4096 x 2048] bf16, MFMA
  {
    dim3 grid(H_ / 128, B_ / 128);
    gemm_mfma_kernel<0><<<grid, 256, 0, stream>>>(
        (const short*)combined_bf, (const short*)W1bf, b1, hidden_bf, B_, D_, H_);
  }

  // 5) logits = hidden @ W2^T + b2  [4096 x 1000] f32, MFMA (Npad=1024)
  {
    dim3 grid(NPAD2 / 128, B_ / 128);
    gemm_mfma_kernel<1><<<grid, 256, 0, stream>>>(
        (const short*)hidden_bf, (const short*)W2bf, b2, logits, B_, H_, C_);
  }

  // 6) scalar head + MSE (partials)
  scalar_loss_kernel<<<B_ / 4, 256, 0, stream>>>(hidden_bf, Ws, bs, tgt_scal, ps);

  // 7) softmax CE + accuracy (partials)
  softmax_loss_kernel<<<B_ / 4, 256, 0, stream>>>(logits, tgt_vec, pv, pa);

  // 8) finalize
  finalize_kernel<<<1, 256, 0, stream>>>(pv, pa, ps, out);
}

// Round 4
// 336.144 us; speedup vs baseline: 2.9610x; 1.0451x over previous
//
#include <hip/hip_runtime.h>
#include <hip/hip_bf16.h>
#include <math.h>

// Problem constants (match reference)
#define B_  4096
#define D_  1024
#define H_  2048
#define C_  1000
#define T_  819200
#define F_  32
#define NPAD2 1024   // W2 rows padded 1000 -> 1024 (row 1000 = Ws, scalar head fused)
#define NPART 1024   // loss partial blocks (B_/4)

typedef __attribute__((ext_vector_type(8))) short short8;
typedef __attribute__((ext_vector_type(4))) float f32x4;

// ---------------- workspace layout (bytes) ----------------
static const size_t WS_SUMS     = 0;                               // B*F f32 = 512K
static const size_t WS_COUNTS   = WS_SUMS + (size_t)B_ * F_ * 4;   // B f32 = 16K
static const size_t WS_ZERO_SZ  = WS_COUNTS + (size_t)B_ * 4;      // zeroed each launch
static const size_t WS_PV       = WS_ZERO_SZ;                      // NPART f32
static const size_t WS_PA       = WS_PV + NPART * 4;
static const size_t WS_PS       = WS_PA + NPART * 4;
static const size_t WS_B2P      = WS_PS + NPART * 4;               // NPAD2 f32 padded bias
static const size_t WS_COMBINED = 1u << 20;                        // B*D bf16 = 8 MiB
static const size_t WS_W1BF     = WS_COMBINED + (size_t)B_ * D_ * 2;   // 4 MiB
static const size_t WS_W2BF     = WS_W1BF + (size_t)H_ * D_ * 2;       // 4 MiB
static const size_t WS_HIDDEN   = WS_W2BF + (size_t)NPAD2 * H_ * 2;    // B*H bf16 = 16 MiB
static const size_t WS_LOGITS   = WS_HIDDEN + (size_t)B_ * H_ * 2;     // B*NPAD2 f32 = 16 MiB

// ---------------- segment mean: run-length reduce (float4) ----------------
#define RPT 32
__global__ __launch_bounds__(256) void seg_reduce_kernel(
    const float* __restrict__ var_flat, const int* __restrict__ seg_ids,
    float* __restrict__ sums, float* __restrict__ counts) {
  int gt  = blockIdx.x * 256 + threadIdx.x;
  int c4  = (gt & 7) * 4;
  long base = (long)(gt >> 3) * RPT;
  int cur = -1;
  float a0 = 0.f, a1 = 0.f, a2 = 0.f, a3 = 0.f, cnt = 0.f;
  for (int r = 0; r < RPT; ++r) {
    long row = base + r;
    int s = seg_ids[row];
    float4 v = *(const float4*)(var_flat + row * F_ + c4);
    if (s != cur) {
      if (cur >= 0) {
        float* dst = &sums[(size_t)cur * F_ + c4];
        atomicAdd(dst + 0, a0); atomicAdd(dst + 1, a1);
        atomicAdd(dst + 2, a2); atomicAdd(dst + 3, a3);
        if (c4 == 0) atomicAdd(&counts[cur], cnt);
      }
      cur = s; a0 = a1 = a2 = a3 = 0.f; cnt = 0.f;
    }
    a0 += v.x; a1 += v.y; a2 += v.z; a3 += v.w; cnt += 1.f;
  }
  if (cur >= 0) {
    float* dst = &sums[(size_t)cur * F_ + c4];
    atomicAdd(dst + 0, a0); atomicAdd(dst + 1, a1);
    atomicAdd(dst + 2, a2); atomicAdd(dst + 3, a3);
    if (c4 == 0) atomicAdd(&counts[cur], cnt);
  }
}

// ---------------- fp32 -> bf16 weight conversion ----------------
__global__ __launch_bounds__(256) void cvt_bf16_kernel(
    const float* __restrict__ src, __hip_bfloat16* __restrict__ dst, int n8) {
  int i = blockIdx.x * 256 + threadIdx.x;
  if (i >= n8) return;
  size_t off = (size_t)i * 8;
  float4 a = *(const float4*)(src + off);
  float4 b = *(const float4*)(src + off + 4);
  __hip_bfloat16 t[8];
  t[0] = __float2bfloat16(a.x); t[1] = __float2bfloat16(a.y);
  t[2] = __float2bfloat16(a.z); t[3] = __float2bfloat16(a.w);
  t[4] = __float2bfloat16(b.x); t[5] = __float2bfloat16(b.y);
  t[6] = __float2bfloat16(b.z); t[7] = __float2bfloat16(b.w);
  *(uint4*)(dst + off) = *(uint4*)t;
}

// W2 [C_,H_] fp32 + Ws [1,H_] -> padded [NPAD2,H_] bf16
// rows 0..999 = W2, row 1000 = Ws, rows 1001+ = 0
__global__ __launch_bounds__(256) void cvt_w2_kernel(
    const float* __restrict__ W2, const float* __restrict__ Ws,
    __hip_bfloat16* __restrict__ dst) {
  int i = blockIdx.x * 256 + threadIdx.x;
  size_t off = (size_t)i * 8;
  int row = (int)(off / H_);
  __hip_bfloat16 t[8];
  const float* src = nullptr;
  if (row < C_)       src = W2 + off;
  else if (row == C_) src = Ws + (off - (size_t)C_ * H_);
  if (src) {
    float4 a = *(const float4*)(src);
    float4 b = *(const float4*)(src + 4);
    t[0] = __float2bfloat16(a.x); t[1] = __float2bfloat16(a.y);
    t[2] = __float2bfloat16(a.z); t[3] = __float2bfloat16(a.w);
    t[4] = __float2bfloat16(b.x); t[5] = __float2bfloat16(b.y);
    t[6] = __float2bfloat16(b.z); t[7] = __float2bfloat16(b.w);
  } else {
    for (int e = 0; e < 8; ++e) t[e] = __float2bfloat16(0.f);
  }
  *(uint4*)(dst + off) = *(uint4*)t;
}

// padded bias: b2p[0..999]=b2, [1000]=bs, rest 0
__global__ __launch_bounds__(256) void pad_bias_kernel(
    const float* __restrict__ b2, const float* __restrict__ bs,
    float* __restrict__ b2p) {
  int i = blockIdx.x * 256 + threadIdx.x;
  float v = 0.f;
  if (i < C_) v = b2[i];
  else if (i == C_) v = bs[0];
  b2p[i] = v;
}

// ---------------- combined = feature + means @ Wv^T + bv (bf16 out) -------
__global__ __launch_bounds__(256) void combined_kernel(
    const float* __restrict__ feat, const float* __restrict__ sums,
    const float* __restrict__ counts, const float* __restrict__ Wv,
    const float* __restrict__ bv, __hip_bfloat16* __restrict__ combined) {
  __shared__ float m[8][F_];
  int b0  = blockIdx.y * 8;
  int tid = threadIdx.x;
  {
    int seg = tid >> 5, col = tid & 31;
    float c = counts[b0 + seg];
    c = c < 1.f ? 1.f : c;
    m[seg][col] = sums[(size_t)(b0 + seg) * F_ + col] / c;
  }
  __syncthreads();
  int d = blockIdx.x * 256 + tid;
  float w[F_];
  {
    const float4* wv = (const float4*)(Wv + (size_t)d * F_);
#pragma unroll
    for (int f4 = 0; f4 < F_ / 4; ++f4) {
      float4 x = wv[f4];
      w[f4 * 4 + 0] = x.x; w[f4 * 4 + 1] = x.y;
      w[f4 * 4 + 2] = x.z; w[f4 * 4 + 3] = x.w;
    }
  }
  float bvd = bv[d];
#pragma unroll
  for (int bb = 0; bb < 8; ++bb) {
    float acc = feat[(size_t)(b0 + bb) * D_ + d] + bvd;
#pragma unroll
    for (int f = 0; f < F_; ++f) acc = fmaf(m[bb][f], w[f], acc);
    combined[(size_t)(b0 + bb) * D_ + d] = __float2bfloat16(acc);
  }
}

// ---------------- MFMA bf16 GEMM, double-buffered LDS ----------------
// C = A @ B^T + bias. 128x128 tile, BK=32, 256 thr (4 waves), one barrier/iter:
// prefetch chunk k+1 into buf^1 right after the barrier, compute chunk k.
__device__ inline void load16_lds(const short* g, short* l) {
  __builtin_amdgcn_global_load_lds(
      (const __attribute__((address_space(1))) void*)g,
      (__attribute__((address_space(3))) void*)l, 16, 0, 0);
}

template <int MODE>  // 0: relu + bf16 out; 1: f32 out (no mask, stride Nout)
__global__ __launch_bounds__(256) void gemm_mfma_kernel(
    const short* __restrict__ A, const short* __restrict__ Bm,
    const float* __restrict__ bias, void* __restrict__ Cout,
    int M, int K, int Nout) {
  __shared__ short As[2][4096];  // 2 x 8 KB
  __shared__ short Bs[2][4096];
  const int tid  = threadIdx.x;
  const int lane = tid & 63;
  const int w    = tid >> 6;
  const int bm = blockIdx.y * 128;
  const int bn = blockIdx.x * 128;
  const int wm = (w >> 1) * 64;
  const int wn = (w & 1) * 64;
  const int m_lane = lane & 15;
  const int quad   = lane >> 4;

  f32x4 acc[4][4];
#pragma unroll
  for (int i = 0; i < 4; ++i)
#pragma unroll
    for (int j = 0; j < 4; ++j) acc[i][j] = f32x4{0.f, 0.f, 0.f, 0.f};

  // staging: 512 16B chunks per tile; chunk c = (kc=c>>7)*8 k-offset, row=c&127.
  const int c0 = w * 128 + lane;
  const int c1 = c0 + 64;
  const short* gA0 = A + (size_t)(bm + (c0 & 127)) * K + (c0 >> 7) * 8;
  const short* gA1 = A + (size_t)(bm + (c1 & 127)) * K + (c1 >> 7) * 8;
  const short* gB0 = Bm + (size_t)(bn + (c0 & 127)) * K + (c0 >> 7) * 8;
  const short* gB1 = Bm + (size_t)(bn + (c1 & 127)) * K + (c1 >> 7) * 8;
  const int l0 = w * 1024;       // wave-uniform LDS base (shorts)
  const int l1 = l0 + 512;

  // prologue: stage chunk 0 into buf 0
  load16_lds(gA0, &As[0][l0]);
  load16_lds(gA1, &As[0][l1]);
  load16_lds(gB0, &Bs[0][l0]);
  load16_lds(gB1, &Bs[0][l1]);

  const int iters = K >> 5;
  for (int it = 0; it < iters; ++it) {
    const int cur = it & 1, nxt = cur ^ 1;
    __syncthreads();   // drains buf[cur] staging; guards buf[nxt] reuse
    const int k1 = (it + 1) << 5;
    if (k1 < K) {
      load16_lds(gA0 + k1, &As[nxt][l0]);
      load16_lds(gA1 + k1, &As[nxt][l1]);
      load16_lds(gB0 + k1, &Bs[nxt][l0]);
      load16_lds(gB1 + k1, &Bs[nxt][l1]);
    }
    short8 af[4], bf[4];
#pragma unroll
    for (int i = 0; i < 4; ++i)
      af[i] = *(const short8*)&As[cur][quad * 1024 + (wm + i * 16 + m_lane) * 8];
#pragma unroll
    for (int j = 0; j < 4; ++j)
      bf[j] = *(const short8*)&Bs[cur][quad * 1024 + (wn + j * 16 + m_lane) * 8];
#pragma unroll
    for (int i = 0; i < 4; ++i)
#pragma unroll
      for (int j = 0; j < 4; ++j)
        acc[i][j] = __builtin_amdgcn_mfma_f32_16x16x32_bf16(af[i], bf[j], acc[i][j], 0, 0, 0);
  }

  // epilogue: C/D layout col=lane&15, row=quad*4+reg
  const int row0 = bm + wm + quad * 4;
  const int col0 = bn + wn + m_lane;
  if (MODE == 0) {
    __hip_bfloat16* Cb = (__hip_bfloat16*)Cout;
#pragma unroll
    for (int j = 0; j < 4; ++j) {
      int col = col0 + j * 16;
      float bsv = bias[col];
#pragma unroll
      for (int i = 0; i < 4; ++i)
#pragma unroll
        for (int r = 0; r < 4; ++r) {
          int row = row0 + i * 16 + r;
          float v = acc[i][j][r] + bsv;
          v = v > 0.f ? v : 0.f;
          Cb[(size_t)row * Nout + col] = __float2bfloat16(v);
        }
    }
  } else {
    float* Cf = (float*)Cout;
#pragma unroll
    for (int j = 0; j < 4; ++j) {
      int col = col0 + j * 16;
      float bsv = bias[col];
#pragma unroll
      for (int i = 0; i < 4; ++i)
#pragma unroll
        for (int r = 0; r < 4; ++r) {
          int row = row0 + i * 16 + r;
          Cf[(size_t)row * Nout + col] = acc[i][j][r] + bsv;
        }
    }
  }
}

// ------- fused loss: softmax CE + accuracy + scalar MSE (col 1000) --------
// 1 wave per row; logits stride NPAD2 (1024 f32 = exactly 4 float4/lane).
__global__ __launch_bounds__(256) void loss_kernel(
    const float* __restrict__ logits, const int* __restrict__ target,
    const float* __restrict__ tgt_scal,
    float* __restrict__ pv, float* __restrict__ pa, float* __restrict__ ps) {
  int tid  = threadIdx.x;
  int lane = tid & 63;
  int w    = tid >> 6;
  int b    = blockIdx.x * 4 + w;
  const float*  row  = logits + (size_t)b * NPAD2;
  const float4* row4 = (const float4*)row;
  float v[16];
  float vmax = -INFINITY;
  int   imax = 0x7fffffff;
#pragma unroll
  for (int k = 0; k < 4; ++k) {
    int c4 = lane + 64 * k;
    float4 x = row4[c4];
    float e0 = x.x, e1 = x.y, e2 = x.z, e3 = x.w;
    int idx = c4 * 4;
    if (idx + 0 >= C_) e0 = -INFINITY;
    if (idx + 1 >= C_) e1 = -INFINITY;
    if (idx + 2 >= C_) e2 = -INFINITY;
    if (idx + 3 >= C_) e3 = -INFINITY;
    v[k * 4 + 0] = e0; v[k * 4 + 1] = e1; v[k * 4 + 2] = e2; v[k * 4 + 3] = e3;
    if (e0 > vmax) { vmax = e0; imax = idx + 0; }
    if (e1 > vmax) { vmax = e1; imax = idx + 1; }
    if (e2 > vmax) { vmax = e2; imax = idx + 2; }
    if (e3 > vmax) { vmax = e3; imax = idx + 3; }
  }
#pragma unroll
  for (int o = 32; o > 0; o >>= 1) {
    float ov = __shfl_down(vmax, o, 64);
    int   oi = __shfl_down(imax, o, 64);
    if (ov > vmax || (ov == vmax && oi < imax)) { vmax = ov; imax = oi; }
  }
  vmax = __shfl(vmax, 0, 64);
  float se = 0.f;
#pragma unroll
  for (int j = 0; j < 16; ++j) se += expf(v[j] - vmax);
#pragma unroll
  for (int o = 32; o > 0; o >>= 1) se += __shfl_down(se, o, 64);
  __shared__ float s_nll[4], s_acc[4], s_sq[4];
  if (lane == 0) {
    int t = target[b];
    float logp = row[t] - vmax - logf(se);
    s_nll[w] = -logp;
    s_acc[w] = (imax == t) ? 1.f : 0.f;
    float d = row[C_] - tgt_scal[b];     // fused scalar head output
    s_sq[w] = d * d;
  }
  __syncthreads();
  if (tid == 0) {
    pv[blockIdx.x] = s_nll[0] + s_nll[1] + s_nll[2] + s_nll[3];
    pa[blockIdx.x] = s_acc[0] + s_acc[1] + s_acc[2] + s_acc[3];
    ps[blockIdx.x] = s_sq[0] + s_sq[1] + s_sq[2] + s_sq[3];
  }
}

// ---------------- finalize: reduce partials ----------------
__global__ __launch_bounds__(256) void finalize_kernel(
    const float* __restrict__ pv, const float* __restrict__ pa,
    const float* __restrict__ ps, float* __restrict__ out) {
  int tid  = threadIdx.x;
  int lane = tid & 63;
  int w    = tid >> 6;
  float nll = 0.f, acc = 0.f, sq = 0.f;
  for (int i = tid; i < NPART; i += 256) {
    nll += pv[i]; acc += pa[i]; sq += ps[i];
  }
#pragma unroll
  for (int o = 32; o > 0; o >>= 1) {
    nll += __shfl_down(nll, o, 64);
    acc += __shfl_down(acc, o, 64);
    sq  += __shfl_down(sq,  o, 64);
  }
  __shared__ float sn[4], sa[4], ss[4];
  if (lane == 0) { sn[w] = nll; sa[w] = acc; ss[w] = sq; }
  __syncthreads();
  if (tid == 0) {
    float lv = (sn[0] + sn[1] + sn[2] + sn[3]) * (1.f / B_);
    float ls = (ss[0] + ss[1] + ss[2] + ss[3]) * (1.f / B_);
    float ac = (sa[0] + sa[1] + sa[2] + sa[3]) * (1.f / B_);
    out[0] = lv + ls;
    out[1] = lv;
    out[2] = ls;
    out[3] = ac;
  }
}

extern "C" void kernel_launch(void* const* d_in, const int* in_sizes, int n_in,
                              void* d_out, int out_size, void* d_ws, size_t ws_size,
                              hipStream_t stream) {
  const float* feature  = (const float*)d_in[0];
  const float* var_flat = (const float*)d_in[1];
  const int*   seg_ids  = (const int*)d_in[2];
  const int*   tgt_vec  = (const int*)d_in[3];
  const float* tgt_scal = (const float*)d_in[4];
  const float* Wv = (const float*)d_in[5];
  const float* bv = (const float*)d_in[6];
  const float* W1 = (const float*)d_in[7];
  const float* b1 = (const float*)d_in[8];
  const float* W2 = (const float*)d_in[9];
  const float* b2 = (const float*)d_in[10];
  const float* Ws = (const float*)d_in[11];
  const float* bs = (const float*)d_in[12];
  float* out = (float*)d_out;

  char* ws = (char*)d_ws;
  float* sums   = (float*)(ws + WS_SUMS);
  float* counts = (float*)(ws + WS_COUNTS);
  float* pv     = (float*)(ws + WS_PV);
  float* pa     = (float*)(ws + WS_PA);
  float* ps     = (float*)(ws + WS_PS);
  float* b2p    = (float*)(ws + WS_B2P);
  __hip_bfloat16* combined_bf = (__hip_bfloat16*)(ws + WS_COMBINED);
  __hip_bfloat16* W1bf        = (__hip_bfloat16*)(ws + WS_W1BF);
  __hip_bfloat16* W2bf        = (__hip_bfloat16*)(ws + WS_W2BF);
  __hip_bfloat16* hidden_bf   = (__hip_bfloat16*)(ws + WS_HIDDEN);
  float*          logits      = (float*)(ws + WS_LOGITS);

  hipMemsetAsync(ws, 0, WS_ZERO_SZ, stream);

  // 1) segment sums/counts
  seg_reduce_kernel<<<(T_ / RPT) * 8 / 256, 256, 0, stream>>>(var_flat, seg_ids, sums, counts);

  // 2) weight conversions (+ scalar-head fusion into W2/bias)
  cvt_bf16_kernel<<<(H_ * D_ / 8 + 255) / 256, 256, 0, stream>>>(W1, W1bf, H_ * D_ / 8);
  cvt_w2_kernel<<<(NPAD2 * H_ / 8) / 256, 256, 0, stream>>>(W2, Ws, W2bf);
  pad_bias_kernel<<<NPAD2 / 256, 256, 0, stream>>>(b2, bs, b2p);

  // 3) combined = feature + means @ Wv^T + bv  (bf16, 8 rows/block)
  {
    dim3 grid(D_ / 256, B_ / 8);
    combined_kernel<<<grid, 256, 0, stream>>>(feature, sums, counts, Wv, bv, combined_bf);
  }

  // 4) hidden = relu(combined @ W1^T + b1)  [4096 x 2048] bf16, MFMA dbuf
  {
    dim3 grid(H_ / 128, B_ / 128);
    gemm_mfma_kernel<0><<<grid, 256, 0, stream>>>(
        (const short*)combined_bf, (const short*)W1bf, b1, hidden_bf, B_, D_, H_);
  }

  // 5) logits[4096 x 1024] = hidden @ W2p^T + b2p  (cols 0..999 = classes,
  //    col 1000 = scalar head), f32, MFMA dbuf
  {
    dim3 grid(NPAD2 / 128, B_ / 128);
    gemm_mfma_kernel<1><<<grid, 256, 0, stream>>>(
        (const short*)hidden_bf, (const short*)W2bf, b2p, logits, B_, H_, NPAD2);
  }

  // 6) fused CE + accuracy + scalar MSE (partials)
  loss_kernel<<<B_ / 4, 256, 0, stream>>>(logits, tgt_vec, tgt_scal, pv, pa, ps);

  // 7) finalize
  finalize_kernel<<<1, 256, 0, stream>>>(pv, pa, ps, out);
}